// Round 17
// baseline (310.702 us; speedup 1.0000x reference)
//
#include <hip/hip_runtime.h>
#include <hip/hip_fp16.h>

#define Nn 100000
#define Ne 1600000
#define Fi 32
#define Hd 64
#define Ll 4
#define Gg 256
#define BN_EPS 1e-5f
#define NPB 128                      // nodes per bucket
#define NBINS ((Nn + NPB - 1) / NPB) // 782 buckets
#define CHUNK 4096                   // edges per partition block
#define NBLK ((Ne + CHUNK - 1) / CHUNK) // 391 partition blocks
#define IDXW (NBINS + 2)             // 784, u16 row stride
#define BSLOT 4096                   // esrc slot per bucket (45 sigma headroom)
#define TPAD 68                      // padded LDS row stride for 64-wide tiles
#define XPAD 36                      // padded LDS row stride for 32-wide tiles
#define NGB ((Nn + 63) / 64)         // 1563 GEMM tiles
#define NSH 128                      // bn-stat shards
#define NB_N ((Nn + 255) / 256)      // 391 node blocks

// ---------------- setup kernels ----------------

// block-major partition (no global atomics, coalesced writes); dst cached in LDS
__global__ __launch_bounds__(256) void k_part(const int* __restrict__ src,
                                              const int* __restrict__ dst,
                                              unsigned* __restrict__ tpack,
                                              unsigned short* __restrict__ idx16) {
    __shared__ int hist[NBINS];
    __shared__ int lofs[NBINS + 1];
    __shared__ int wsum[256];
    __shared__ unsigned stage[CHUNK];
    __shared__ int dbuf[CHUNK];
    int blk = blockIdx.x, t = threadIdx.x;
    int e0 = blk * CHUNK;
    int nval = min(CHUNK, Ne - e0);

    for (int i = t; i < NBINS; i += 256) hist[i] = 0;
    for (int i = t; i < nval; i += 256) dbuf[i] = dst[e0 + i];
    __syncthreads();
    for (int i = t; i < nval; i += 256)
        atomicAdd(&hist[dbuf[i] >> 7], 1);
    __syncthreads();

    int base = t * 4;
    int loc[4];
    int s = 0;
#pragma unroll
    for (int k = 0; k < 4; k++) {
        int b = base + k;
        int c = (b < NBINS) ? hist[b] : 0;
        loc[k] = s;
        s += c;
    }
    wsum[t] = s;
    __syncthreads();
    int x = s;
    for (int off = 1; off < 256; off <<= 1) {
        int u = (t >= off) ? wsum[t - off] : 0;
        __syncthreads();
        x += u;
        wsum[t] = x;
        __syncthreads();
    }
    int excl = x - s;
#pragma unroll
    for (int k = 0; k < 4; k++) {
        int b = base + k;
        if (b < NBINS) lofs[b] = excl + loc[k];
    }
    if (t == 0) lofs[NBINS] = nval;
    __syncthreads();

    for (int i = t; i <= NBINS; i += 256)
        idx16[(size_t)blk * IDXW + i] = (unsigned short)lofs[i];

    for (int i = t; i < NBINS; i += 256) hist[i] = lofs[i];
    __syncthreads();
    for (int i = t; i < nval; i += 256) {
        int d = dbuf[i];
        int sv = src[e0 + i];
        int p = atomicAdd(&hist[d >> 7], 1);
        stage[p] = (unsigned)sv | ((unsigned)(d & (NPB - 1)) << 17);
    }
    __syncthreads();
    for (int i = t; i < nval; i += 256)
        tpack[(size_t)blk * CHUNK + i] = stage[i];
}

// one-shot per-bucket CSR build; block NBINS handles gstart.
__global__ __launch_bounds__(512) void k_csr2(const unsigned* __restrict__ tpack,
                                              const unsigned short* __restrict__ idx16,
                                              const int* __restrict__ batch,
                                              int* __restrict__ esrc,
                                              int* __restrict__ row_off,
                                              int* __restrict__ rdeg,
                                              float* __restrict__ dinv,
                                              int* __restrict__ gstart) {
    int t = threadIdx.x;
    if (blockIdx.x == NBINS) {
        if (t < Gg) {
            int lo = 0, hi = Nn;
            while (lo < hi) {
                int mid = (lo + hi) >> 1;
                if (batch[mid] < t) lo = mid + 1; else hi = mid;
            }
            gstart[t] = lo;
            if (t == 0) gstart[Gg] = Nn;
        }
        return;
    }
    __shared__ unsigned edges[BSLOT];
    __shared__ unsigned ordered[BSLOT];
    __shared__ int rlen[512];
    __shared__ int cnt[NPB], startv[NPB], cur[NPB];
    int b = blockIdx.x;
    int n0 = b * NPB;
    int base = b * BSLOT;

    int len = 0, s0 = 0;
    if (t < NBLK) {
        const unsigned short* row = idx16 + (size_t)t * IDXW;
        s0 = row[b];
        len = (int)row[b + 1] - s0;
    }
    rlen[t] = len;
    __syncthreads();
    int x = len;
    for (int off = 1; off < 512; off <<= 1) {
        int u = (t >= off) ? rlen[t - off] : 0;
        __syncthreads();
        x += u;
        rlen[t] = x;
        __syncthreads();
    }
    int lput = x - len;
    int total = rlen[511];
    if (t < NBLK && len > 0) {
        const unsigned* tp = tpack + (size_t)t * CHUNK + s0;
        for (int k = 0; k < len; k++)
            edges[lput + k] = tp[k];
    }
    if (t < NPB) cnt[t] = 0;
    __syncthreads();
    for (int i = t; i < total; i += 512)
        atomicAdd(&cnt[edges[i] >> 17], 1);
    __syncthreads();
    if (t < NPB) startv[t] = cnt[t];
    __syncthreads();
    for (int off = 1; off < NPB; off <<= 1) {
        int u = (t < NPB && t >= off) ? startv[t - off] : 0;
        __syncthreads();
        if (t < NPB) startv[t] += u;
        __syncthreads();
    }
    if (t < NPB) {
        int st = startv[t] - cnt[t];
        cur[t] = st;
        int node = n0 + t;
        if (node < Nn) {
            row_off[node] = base + st;
            rdeg[node] = cnt[t];
            dinv[node] = rsqrtf((float)cnt[t] + 1.0f);
        }
    }
    __syncthreads();
    for (int i = t; i < total; i += 512) {
        unsigned v = edges[i];
        int p = atomicAdd(&cur[v >> 17], 1);
        ordered[p] = v & 0x1FFFFu;
    }
    __syncthreads();
    for (int i = t; i < total; i += 512)
        esrc[base + i] = (int)ordered[i];
}

// ---------------- degree-sort (counting sort, sharded) ----------------

// per-block LDS degree histogram -> sharded global hist gh[shard][bin]
__global__ __launch_bounds__(256) void k_sortA(const int* __restrict__ rdeg,
                                               int* __restrict__ gh) {
    __shared__ int lh[64];
    int t = threadIdx.x, b = blockIdx.x;
    if (t < 64) lh[t] = 0;
    __syncthreads();
    int i = b * 256 + t;
    if (i < Nn) atomicAdd(&lh[min(rdeg[i], 63)], 1);
    __syncthreads();
    if (t < 64 && lh[t])
        atomicAdd(&gh[(b & 63) * 64 + t], lh[t]);
}

// exclusive scan of gh over (bin, shard) sequence -> start offsets
__global__ __launch_bounds__(512) void k_sortB(int* __restrict__ gh) {
    __shared__ int part[512];
    int t = threadIdx.x;
    int s0 = t * 8;
    int loc[8];
    int sum = 0;
#pragma unroll
    for (int k = 0; k < 8; k++) {
        int seq = s0 + k;
        int bin = seq >> 6, shard = seq & 63;
        loc[k] = sum;
        sum += gh[shard * 64 + bin];
    }
    part[t] = sum;
    __syncthreads();
    int x = sum;
    for (int off = 1; off < 512; off <<= 1) {
        int u = (t >= off) ? part[t - off] : 0;
        __syncthreads();
        x += u;
        part[t] = x;
        __syncthreads();
    }
    int excl = x - sum;
#pragma unroll
    for (int k = 0; k < 8; k++) {
        int seq = s0 + k;
        int bin = seq >> 6, shard = seq & 63;
        gh[shard * 64 + bin] = excl + loc[k];
    }
}

// place nodes into perm by (degree, shard) order
__global__ __launch_bounds__(256) void k_sortC(const int* __restrict__ rdeg,
                                               int* __restrict__ gh,
                                               int* __restrict__ perm) {
    int t = threadIdx.x, b = blockIdx.x;
    int i = b * 256 + t;
    if (i < Nn) {
        int bin = min(rdeg[i], 63);
        int pos = atomicAdd(&gh[(b & 63) * 64 + bin], 1);
        perm[pos] = i;
    }
}

// ---------------- tiled GEMM kernels ----------------

#define MT_FMA(AV, W0, W1, W2, W3, R)                                          \
    acc[R][0] = fmaf(AV.x, W0.x, acc[R][0]);                                   \
    acc[R][0] = fmaf(AV.y, W1.x, acc[R][0]);                                   \
    acc[R][0] = fmaf(AV.z, W2.x, acc[R][0]);                                   \
    acc[R][0] = fmaf(AV.w, W3.x, acc[R][0]);                                   \
    acc[R][1] = fmaf(AV.x, W0.y, acc[R][1]);                                   \
    acc[R][1] = fmaf(AV.y, W1.y, acc[R][1]);                                   \
    acc[R][1] = fmaf(AV.z, W2.y, acc[R][1]);                                   \
    acc[R][1] = fmaf(AV.w, W3.y, acc[R][1]);                                   \
    acc[R][2] = fmaf(AV.x, W0.z, acc[R][2]);                                   \
    acc[R][2] = fmaf(AV.y, W1.z, acc[R][2]);                                   \
    acc[R][2] = fmaf(AV.z, W2.z, acc[R][2]);                                   \
    acc[R][2] = fmaf(AV.w, W3.z, acc[R][2]);                                   \
    acc[R][3] = fmaf(AV.x, W0.w, acc[R][3]);                                   \
    acc[R][3] = fmaf(AV.y, W1.w, acc[R][3]);                                   \
    acc[R][3] = fmaf(AV.z, W2.w, acc[R][3]);                                   \
    acc[R][3] = fmaf(AV.w, W3.w, acc[R][3]);

__device__ inline void store_half4(unsigned short* dst, float a, float b,
                                   float c, float d) {
    __half2 p0 = __floats2half2_rn(a, b);
    __half2 p1 = __floats2half2_rn(c, d);
    uint2 u;
    u.x = *(unsigned*)&p0;
    u.y = *(unsigned*)&p1;
    *(uint2*)dst = u;
}

__device__ inline void store_half8(unsigned short* dst, const float* a) {
    __half2 p0 = __floats2half2_rn(a[0], a[1]);
    __half2 p1 = __floats2half2_rn(a[2], a[3]);
    __half2 p2 = __floats2half2_rn(a[4], a[5]);
    __half2 p3 = __floats2half2_rn(a[6], a[7]);
    uint4 u;
    u.x = *(unsigned*)&p0; u.y = *(unsigned*)&p1;
    u.z = *(unsigned*)&p2; u.w = *(unsigned*)&p3;
    *(uint4*)dst = u;
}

__device__ inline float4 load_half4(const unsigned short* p) {
    uint2 u = *(const uint2*)p;
    float2 f0 = __half22float2(*(__half2*)&u.x);
    float2 f1 = __half22float2(*(__half2*)&u.y);
    return make_float4(f0.x, f0.y, f1.x, f1.y);
}

// fused: bnfinal + hn = relu(agg*sc+sh)+h (h fp16, rewritten), hw = hn@W;
// store hwh = hw*dinv (fp16)
__global__ __launch_bounds__(256, 4) void k_gemmF2(const unsigned short* __restrict__ aggh,
                                                   const float* __restrict__ bnacc,
                                                   const float* __restrict__ gamma,
                                                   const float* __restrict__ beta,
                                                   unsigned short* __restrict__ hh,
                                                   const float* __restrict__ W,
                                                   const float* __restrict__ dinv,
                                                   unsigned short* __restrict__ hwh) {
    __shared__ float hs[64 * TPAD];
    __shared__ float ws[64 * 64];
    __shared__ float bsc[64], bsh[64];
    int t = threadIdx.x;
    int n0 = blockIdx.x * 64;

    for (int f = t; f < 1024; f += 256)
        ((float4*)ws)[f] = ((const float4*)W)[f];

    if (t < 64) {
        float s = 0.f, s2 = 0.f;
        for (int shd = 0; shd < NSH; shd++) {
            s  += bnacc[shd * 128 + t];
            s2 += bnacc[shd * 128 + 64 + t];
        }
        float mean = s / (float)Nn;
        float var = fmaxf(s2 / (float)Nn - mean * mean, 0.f);
        float scv = gamma[t] * rsqrtf(var + BN_EPS);
        bsc[t] = scv;
        bsh[t] = beta[t] - mean * scv;
    }
    __syncthreads();

    for (int f = t; f < 1024; f += 256) {
        int row = f >> 4, c4 = (f & 15) * 4;
        int node = n0 + row;
        if (node < Nn) {
            float4 a  = load_half4(aggh + (size_t)node * Hd + c4);
            float4 ho = load_half4(hh + (size_t)node * Hd + c4);
            float4 sc = ((const float4*)bsc)[f & 15];
            float4 sh = ((const float4*)bsh)[f & 15];
            float4 r4;
            r4.x = fmaxf(fmaf(a.x, sc.x, sh.x), 0.f) + ho.x;
            r4.y = fmaxf(fmaf(a.y, sc.y, sh.y), 0.f) + ho.y;
            r4.z = fmaxf(fmaf(a.z, sc.z, sh.z), 0.f) + ho.z;
            r4.w = fmaxf(fmaf(a.w, sc.w, sh.w), 0.f) + ho.w;
            store_half4(hh + (size_t)node * Hd + c4, r4.x, r4.y, r4.z, r4.w);
            *(float4*)&hs[row * TPAD + c4] = r4;
        } else {
            *(float4*)&hs[row * TPAD + c4] = make_float4(0.f, 0.f, 0.f, 0.f);
        }
    }
    __syncthreads();

    int i = t >> 4, j = t & 15;
    float acc[4][4] = {};
#pragma unroll 2
    for (int k = 0; k < 64; k += 4) {
        float4 w0 = *(const float4*)&ws[(k + 0) * 64 + 4 * j];
        float4 w1 = *(const float4*)&ws[(k + 1) * 64 + 4 * j];
        float4 w2 = *(const float4*)&ws[(k + 2) * 64 + 4 * j];
        float4 w3 = *(const float4*)&ws[(k + 3) * 64 + 4 * j];
        float4 a0 = *(const float4*)&hs[(4 * i + 0) * TPAD + k];
        float4 a1 = *(const float4*)&hs[(4 * i + 1) * TPAD + k];
        float4 a2 = *(const float4*)&hs[(4 * i + 2) * TPAD + k];
        float4 a3 = *(const float4*)&hs[(4 * i + 3) * TPAD + k];
        MT_FMA(a0, w0, w1, w2, w3, 0)
        MT_FMA(a1, w0, w1, w2, w3, 1)
        MT_FMA(a2, w0, w1, w2, w3, 2)
        MT_FMA(a3, w0, w1, w2, w3, 3)
    }
#pragma unroll
    for (int r = 0; r < 4; r++) {
        int node = n0 + 4 * i + r;
        if (node < Nn) {
            float dv = dinv[node];
            store_half4(hwh + (size_t)node * Hd + 4 * j,
                        acc[r][0] * dv, acc[r][1] * dv, acc[r][2] * dv,
                        acc[r][3] * dv);
        }
    }
}

// fused: h = x@we+be (write hh fp16), hw = h@W0; store hwh = hw*dinv (fp16)
__global__ __launch_bounds__(256, 4) void k_embed_gemm2(const float* __restrict__ x,
                                                        const float* __restrict__ we,
                                                        const float* __restrict__ be,
                                                        const float* __restrict__ W,
                                                        unsigned short* __restrict__ hh,
                                                        const float* __restrict__ dinv,
                                                        unsigned short* __restrict__ hwh) {
    __shared__ float uni[64 * XPAD + 32 * 64];
    __shared__ float hs[64 * TPAD];
    __shared__ float bes[64];
    float* xs  = uni;
    float* wes = uni + 64 * XPAD;
    float* ws  = uni;
    int t = threadIdx.x;
    int n0 = blockIdx.x * 64;

    for (int f = t; f < 512; f += 256)
        ((float4*)wes)[f] = ((const float4*)we)[f];
    if (t < 64) bes[t] = be[t];

    for (int f = t; f < 512; f += 256) {
        int row = f >> 3, c4 = (f & 7) * 4;
        int node = n0 + row;
        float4 v = (node < Nn) ? *(const float4*)(x + (size_t)node * Fi + c4)
                               : make_float4(0.f, 0.f, 0.f, 0.f);
        *(float4*)&xs[row * XPAD + c4] = v;
    }
    __syncthreads();

    int i = t >> 4, j = t & 15;
    {
        float acc[4][4];
#pragma unroll
        for (int r = 0; r < 4; r++)
#pragma unroll
            for (int c = 0; c < 4; c++) acc[r][c] = bes[4 * j + c];
#pragma unroll 2
        for (int k = 0; k < 32; k += 4) {
            float4 w0 = *(const float4*)&wes[(k + 0) * 64 + 4 * j];
            float4 w1 = *(const float4*)&wes[(k + 1) * 64 + 4 * j];
            float4 w2 = *(const float4*)&wes[(k + 2) * 64 + 4 * j];
            float4 w3 = *(const float4*)&wes[(k + 3) * 64 + 4 * j];
            float4 a0 = *(const float4*)&xs[(4 * i + 0) * XPAD + k];
            float4 a1 = *(const float4*)&xs[(4 * i + 1) * XPAD + k];
            float4 a2 = *(const float4*)&xs[(4 * i + 2) * XPAD + k];
            float4 a3 = *(const float4*)&xs[(4 * i + 3) * XPAD + k];
            MT_FMA(a0, w0, w1, w2, w3, 0)
            MT_FMA(a1, w0, w1, w2, w3, 1)
            MT_FMA(a2, w0, w1, w2, w3, 2)
            MT_FMA(a3, w0, w1, w2, w3, 3)
        }
#pragma unroll
        for (int r = 0; r < 4; r++) {
            int node = n0 + 4 * i + r;
            float4 hv = make_float4(acc[r][0], acc[r][1], acc[r][2], acc[r][3]);
            *(float4*)&hs[(4 * i + r) * TPAD + 4 * j] = hv;
            if (node < Nn)
                store_half4(hh + (size_t)node * Hd + 4 * j, hv.x, hv.y, hv.z, hv.w);
        }
    }
    __syncthreads();
    for (int f = t; f < 1024; f += 256)
        ((float4*)ws)[f] = ((const float4*)W)[f];
    __syncthreads();
    {
        float acc[4][4] = {};
#pragma unroll 2
        for (int k = 0; k < 64; k += 4) {
            float4 w0 = *(const float4*)&ws[(k + 0) * 64 + 4 * j];
            float4 w1 = *(const float4*)&ws[(k + 1) * 64 + 4 * j];
            float4 w2 = *(const float4*)&ws[(k + 2) * 64 + 4 * j];
            float4 w3 = *(const float4*)&ws[(k + 3) * 64 + 4 * j];
            float4 a0 = *(const float4*)&hs[(4 * i + 0) * TPAD + k];
            float4 a1 = *(const float4*)&hs[(4 * i + 1) * TPAD + k];
            float4 a2 = *(const float4*)&hs[(4 * i + 2) * TPAD + k];
            float4 a3 = *(const float4*)&hs[(4 * i + 3) * TPAD + k];
            MT_FMA(a0, w0, w1, w2, w3, 0)
            MT_FMA(a1, w0, w1, w2, w3, 1)
            MT_FMA(a2, w0, w1, w2, w3, 2)
            MT_FMA(a3, w0, w1, w2, w3, 3)
        }
#pragma unroll
        for (int r = 0; r < 4; r++) {
            int node = n0 + 4 * i + r;
            if (node < Nn) {
                float dv = dinv[node];
                store_half4(hwh + (size_t)node * Hd + 4 * j,
                            acc[r][0] * dv, acc[r][1] * dv, acc[r][2] * dv,
                            acc[r][3] * dv);
            }
        }
    }
}

// ---------------- gather / pool / head ----------------

// gather on pre-scaled rows, degree-sorted node order via perm:
// agg[node] = (sum_src hwh[src] + hwh[node]) * dinv[node] + bias
__global__ __launch_bounds__(256) void k_gatherH(const unsigned short* __restrict__ hwh,
                                                 const float* __restrict__ dinv,
                                                 const int* __restrict__ row_off,
                                                 const int* __restrict__ rdeg,
                                                 const int* __restrict__ esrc,
                                                 const int* __restrict__ perm,
                                                 const float* __restrict__ bias,
                                                 unsigned short* __restrict__ aggh,
                                                 float* __restrict__ bnacc) {
    int g = threadIdx.x >> 3;   // 32 node slots
    int l = threadIdx.x & 7;    // lane in node group
    int node = perm[blockIdx.x * 32 + g];   // degree-sorted
    float di = dinv[node];
    float acc[8];

    uint4 v = *(const uint4*)(hwh + (size_t)node * Hd + l * 8);
#pragma unroll
    for (int q = 0; q < 4; q++) {
        float2 f = __half22float2(*(__half2*)(((unsigned*)&v) + q));
        acc[2 * q]     = f.x;
        acc[2 * q + 1] = f.y;
    }

    int e = row_off[node];
    int e1 = e + rdeg[node];
    for (; e + 7 < e1; e += 8) {
        uint4 vv[8];
#pragma unroll
        for (int u = 0; u < 8; u++)
            vv[u] = *(const uint4*)(hwh + (size_t)esrc[e + u] * Hd + l * 8);
#pragma unroll
        for (int u = 0; u < 8; u++) {
#pragma unroll
            for (int q = 0; q < 4; q++) {
                float2 f = __half22float2(*(__half2*)(((unsigned*)&vv[u]) + q));
                acc[2 * q]     += f.x;
                acc[2 * q + 1] += f.y;
            }
        }
    }
    for (; e + 1 < e1; e += 2) {
        uint4 v0 = *(const uint4*)(hwh + (size_t)esrc[e] * Hd + l * 8);
        uint4 v1 = *(const uint4*)(hwh + (size_t)esrc[e + 1] * Hd + l * 8);
#pragma unroll
        for (int q = 0; q < 4; q++) {
            float2 f0 = __half22float2(*(__half2*)(((unsigned*)&v0) + q));
            float2 f1 = __half22float2(*(__half2*)(((unsigned*)&v1) + q));
            acc[2 * q]     += f0.x + f1.x;
            acc[2 * q + 1] += f0.y + f1.y;
        }
    }
    if (e < e1) {
        uint4 v0 = *(const uint4*)(hwh + (size_t)esrc[e] * Hd + l * 8);
#pragma unroll
        for (int q = 0; q < 4; q++) {
            float2 f0 = __half22float2(*(__half2*)(((unsigned*)&v0) + q));
            acc[2 * q]     += f0.x;
            acc[2 * q + 1] += f0.y;
        }
    }

#pragma unroll
    for (int q = 0; q < 8; q++)
        acc[q] = fmaf(acc[q], di, bias[l * 8 + q]);

    store_half8(aggh + (size_t)node * Hd + l * 8, acc);

    // bn stats: block reduce over 32 node slots, sharded atomics
    __shared__ float ls[2048];
    *(float4*)&ls[g * 64 + l * 8]     = make_float4(acc[0], acc[1], acc[2], acc[3]);
    *(float4*)&ls[g * 64 + l * 8 + 4] = make_float4(acc[4], acc[5], acc[6], acc[7]);
    __syncthreads();
    int t = threadIdx.x;
    if (t < 64) {
        float s = 0.f, s2 = 0.f;
#pragma unroll
        for (int gg = 0; gg < 32; gg++) {
            float vv = ls[gg * 64 + t];
            s += vv;
            s2 = fmaf(vv, vv, s2);
        }
        float* a = bnacc + (blockIdx.x & (NSH - 1)) * 128;
        atomicAdd(&a[t], s);
        atomicAdd(&a[64 + t], s2);
    }
}

// fused: bnfinal + final bn-apply + relu + residual + per-graph mean pool
__global__ __launch_bounds__(1024) void k_poolF(const unsigned short* __restrict__ aggh,
                                                const float* __restrict__ bnacc,
                                                const float* __restrict__ gamma,
                                                const float* __restrict__ beta,
                                                const unsigned short* __restrict__ hh,
                                                const int* __restrict__ gstart,
                                                float* __restrict__ pooled) {
    __shared__ float ls[1024];
    __shared__ float bsc[64], bsh[64];
    int g = blockIdx.x;
    int t = threadIdx.x;
    if (t < 64) {
        float s = 0.f, s2 = 0.f;
        for (int shd = 0; shd < NSH; shd++) {
            s  += bnacc[shd * 128 + t];
            s2 += bnacc[shd * 128 + 64 + t];
        }
        float mean = s / (float)Nn;
        float var = fmaxf(s2 / (float)Nn - mean * mean, 0.f);
        float scv = gamma[t] * rsqrtf(var + BN_EPS);
        bsc[t] = scv;
        bsh[t] = beta[t] - mean * scv;
    }
    __syncthreads();
    int ch = t & 63, sl = t >> 6;
    float sc = bsc[ch], shv = bsh[ch];
    int n0 = gstart[g], n1 = gstart[g + 1];
    float s = 0.f;
    for (int n = n0 + sl; n < n1; n += 16) {
        float a  = __half2float(((const __half*)aggh)[(size_t)n * Hd + ch]);
        float ho = __half2float(((const __half*)hh)[(size_t)n * Hd + ch]);
        s += fmaxf(fmaf(a, sc, shv), 0.f) + ho;
    }
    ls[t] = s;
    __syncthreads();
    if (t < 64) {
        float acc = 0.f;
#pragma unroll
        for (int k = 0; k < 16; k++) acc += ls[k * 64 + t];
        float cnt = (float)(n1 - n0);
        pooled[g * Hd + t] = acc / fmaxf(cnt, 1.0f);
    }
}

__global__ __launch_bounds__(256) void k_head(const float* __restrict__ pooled,
                                              const float* __restrict__ w1,
                                              const float* __restrict__ b1,
                                              const float* __restrict__ w2,
                                              const float* __restrict__ b2,
                                              float* __restrict__ out) {
    __shared__ float sw1[Hd * 32], sw2[32], sb1[32];
    int t = threadIdx.x;
    for (int i = t; i < Hd * 32; i += 256) sw1[i] = w1[i];
    if (t < 32) { sw2[t] = w2[t]; sb1[t] = b1[t]; }
    __syncthreads();
    float acc2[32];
#pragma unroll
    for (int k = 0; k < 32; k++) acc2[k] = sb1[k];
    for (int j = 0; j < Hd; j++) {
        float pj = pooled[t * Hd + j];
#pragma unroll
        for (int k = 0; k < 32; k++) acc2[k] = fmaf(pj, sw1[j * 32 + k], acc2[k]);
    }
    float o = b2[0];
#pragma unroll
    for (int k = 0; k < 32; k++) o += fmaxf(acc2[k], 0.f) * sw2[k];
    out[t] = o;
}

// ---------------- launch ----------------

extern "C" void kernel_launch(void* const* d_in, const int* in_sizes, int n_in,
                              void* d_out, int out_size, void* d_ws, size_t ws_size,
                              hipStream_t stream) {
    const float* x       = (const float*)d_in[0];
    const int*   eidx    = (const int*)d_in[1];
    const int*   batch   = (const int*)d_in[2];
    const float* w_embed = (const float*)d_in[3];
    const float* b_embed = (const float*)d_in[4];
    const float* conv_W  = (const float*)d_in[5];
    const float* conv_b  = (const float*)d_in[6];
    const float* gamma   = (const float*)d_in[7];
    const float* beta    = (const float*)d_in[8];
    const float* w1      = (const float*)d_in[9];
    const float* b1      = (const float*)d_in[10];
    const float* w2      = (const float*)d_in[11];
    const float* b2      = (const float*)d_in[12];
    const int* src = eidx;
    const int* dst = eidx + Ne;

    char* p = (char*)d_ws;
    auto alloc = [&](size_t bytes) -> void* {
        void* r = (void*)p;
        p += (bytes + 255) / 256 * 256;
        return r;
    };
    unsigned short* hh  = (unsigned short*)alloc((size_t)Nn * Hd * 2);
    unsigned short* hwh = (unsigned short*)alloc((size_t)Nn * Hd * 2);
    unsigned short* aggh = (unsigned short*)alloc((size_t)Nn * Hd * 2);
    int*      row_off = (int*)alloc((size_t)Nn * 4);
    int*      rdeg    = (int*)alloc((size_t)Nn * 4);
    float*    dinv    = (float*)alloc((size_t)Nn * 4);
    int*      perm    = (int*)alloc((size_t)Nn * 4);
    int*      esrc    = (int*)alloc((size_t)NBINS * BSLOT * 4);
    unsigned* tpack   = (unsigned*)alloc((size_t)NBLK * CHUNK * 4);
    unsigned short* idx16 = (unsigned short*)alloc((size_t)NBLK * IDXW * 2);
    int*      gh      = (int*)alloc(64 * 64 * 4);           // 16384 B, 256-aligned
    float*    bnacc   = (float*)alloc((size_t)Ll * NSH * 128 * 4);  // contiguous after gh
    float*    pooled  = (float*)alloc((size_t)Gg * Hd * 4);
    int*      gstart  = (int*)alloc((size_t)(Gg + 1) * 4);
    (void)ws_size; (void)in_sizes; (void)n_in; (void)out_size;

    const int NB_G32 = Nn / 32;              // 3125 gather blocks

    // gh and bnacc are contiguous: one memset for both
    hipMemsetAsync(gh, 0, 64 * 64 * 4 + (size_t)Ll * NSH * 128 * 4, stream);

    k_part<<<NBLK, 256, 0, stream>>>(src, dst, tpack, idx16);
    k_csr2<<<NBINS + 1, 512, 0, stream>>>(tpack, idx16, batch, esrc, row_off,
                                          rdeg, dinv, gstart);
    k_sortA<<<NB_N, 256, 0, stream>>>(rdeg, gh);
    k_sortB<<<1, 512, 0, stream>>>(gh);
    k_sortC<<<NB_N, 256, 0, stream>>>(rdeg, gh, perm);

    k_embed_gemm2<<<NGB, 256, 0, stream>>>(x, w_embed, b_embed, conv_W, hh, dinv, hwh);

    for (int i = 0; i < Ll; i++) {
        if (i > 0)
            k_gemmF2<<<NGB, 256, 0, stream>>>(aggh, bnacc + (size_t)(i - 1) * NSH * 128,
                                              gamma + (size_t)(i - 1) * Hd,
                                              beta + (size_t)(i - 1) * Hd, hh,
                                              conv_W + (size_t)i * Hd * Hd, dinv, hwh);
        k_gatherH<<<NB_G32, 256, 0, stream>>>(hwh, dinv, row_off, rdeg, esrc, perm,
                                              conv_b + (size_t)i * Hd, aggh,
                                              bnacc + (size_t)i * NSH * 128);
    }

    k_poolF<<<Gg, 1024, 0, stream>>>(aggh, bnacc + (size_t)(Ll - 1) * NSH * 128,
                                     gamma + (size_t)(Ll - 1) * Hd,
                                     beta + (size_t)(Ll - 1) * Hd, hh, gstart, pooled);
    k_head<<<1, 256, 0, stream>>>(pooled, w1, b1, w2, b2, (float*)d_out);
}

// Round 18
// 293.348 us; speedup vs baseline: 1.0592x; 1.0592x over previous
//
#include <hip/hip_runtime.h>
#include <hip/hip_fp16.h>

#define Nn 100000
#define Ne 1600000
#define Fi 32
#define Hd 64
#define Ll 4
#define Gg 256
#define BN_EPS 1e-5f
#define NPB 128                      // nodes per bucket
#define NBINS ((Nn + NPB - 1) / NPB) // 782 buckets
#define CHUNK 4096                   // edges per partition block
#define NBLK ((Ne + CHUNK - 1) / CHUNK) // 391 partition blocks
#define IDXW (NBINS + 2)             // 784, u16 row stride
#define BSLOT 4096                   // esrc slot per bucket (45 sigma headroom)
#define TPAD 68                      // padded LDS row stride for 64-wide tiles
#define XPAD 36                      // padded LDS row stride for 32-wide tiles
#define NGB ((Nn + 63) / 64)         // 1563 GEMM tiles
#define NSH 128                      // bn-stat shards

// ---------------- setup kernels ----------------

// block-major partition (no global atomics, coalesced writes)
__global__ __launch_bounds__(256) void k_part(const int* __restrict__ src,
                                              const int* __restrict__ dst,
                                              unsigned* __restrict__ tpack,
                                              unsigned short* __restrict__ idx16) {
    __shared__ int hist[NBINS];
    __shared__ int lofs[NBINS + 1];
    __shared__ int wsum[256];
    __shared__ unsigned stage[CHUNK];
    int blk = blockIdx.x, t = threadIdx.x;
    int e0 = blk * CHUNK;
    int nval = min(CHUNK, Ne - e0);

    for (int i = t; i < NBINS; i += 256) hist[i] = 0;
    __syncthreads();
    for (int i = t; i < nval; i += 256)
        atomicAdd(&hist[dst[e0 + i] >> 7], 1);
    __syncthreads();

    int base = t * 4;
    int loc[4];
    int s = 0;
#pragma unroll
    for (int k = 0; k < 4; k++) {
        int b = base + k;
        int c = (b < NBINS) ? hist[b] : 0;
        loc[k] = s;
        s += c;
    }
    wsum[t] = s;
    __syncthreads();
    int x = s;
    for (int off = 1; off < 256; off <<= 1) {
        int u = (t >= off) ? wsum[t - off] : 0;
        __syncthreads();
        x += u;
        wsum[t] = x;
        __syncthreads();
    }
    int excl = x - s;
#pragma unroll
    for (int k = 0; k < 4; k++) {
        int b = base + k;
        if (b < NBINS) lofs[b] = excl + loc[k];
    }
    if (t == 0) lofs[NBINS] = nval;
    __syncthreads();

    for (int i = t; i <= NBINS; i += 256)
        idx16[(size_t)blk * IDXW + i] = (unsigned short)lofs[i];

    for (int i = t; i < NBINS; i += 256) hist[i] = lofs[i];
    __syncthreads();
    for (int i = t; i < nval; i += 256) {
        int d = dst[e0 + i];
        int sv = src[e0 + i];
        int p = atomicAdd(&hist[d >> 7], 1);
        stage[p] = (unsigned)sv | ((unsigned)(d & (NPB - 1)) << 17);
    }
    __syncthreads();
    for (int i = t; i < nval; i += 256)
        tpack[(size_t)blk * CHUNK + i] = stage[i];
}

// one-shot per-bucket CSR build: stage runs in LDS, histogram, local scan,
// write row_off/rdeg/dinv + reordered esrc (slot-based, no global scan).
// block NBINS handles gstart.
__global__ __launch_bounds__(512) void k_csr2(const unsigned* __restrict__ tpack,
                                              const unsigned short* __restrict__ idx16,
                                              const int* __restrict__ batch,
                                              int* __restrict__ esrc,
                                              int* __restrict__ row_off,
                                              int* __restrict__ rdeg,
                                              float* __restrict__ dinv,
                                              int* __restrict__ gstart) {
    int t = threadIdx.x;
    if (blockIdx.x == NBINS) {
        if (t < Gg) {
            int lo = 0, hi = Nn;
            while (lo < hi) {
                int mid = (lo + hi) >> 1;
                if (batch[mid] < t) lo = mid + 1; else hi = mid;
            }
            gstart[t] = lo;
            if (t == 0) gstart[Gg] = Nn;
        }
        return;
    }
    __shared__ unsigned edges[BSLOT];
    __shared__ unsigned ordered[BSLOT];
    __shared__ int rlen[512];
    __shared__ int cnt[NPB], startv[NPB], cur[NPB];
    int b = blockIdx.x;
    int n0 = b * NPB;
    int base = b * BSLOT;

    int len = 0, s0 = 0;
    if (t < NBLK) {
        const unsigned short* row = idx16 + (size_t)t * IDXW;
        s0 = row[b];
        len = (int)row[b + 1] - s0;
    }
    rlen[t] = len;
    __syncthreads();
    int x = len;
    for (int off = 1; off < 512; off <<= 1) {
        int u = (t >= off) ? rlen[t - off] : 0;
        __syncthreads();
        x += u;
        rlen[t] = x;
        __syncthreads();
    }
    int lput = x - len;
    int total = rlen[511];
    if (t < NBLK && len > 0) {
        const unsigned* tp = tpack + (size_t)t * CHUNK + s0;
        for (int k = 0; k < len; k++)
            edges[lput + k] = tp[k];
    }
    if (t < NPB) cnt[t] = 0;
    __syncthreads();
    for (int i = t; i < total; i += 512)
        atomicAdd(&cnt[edges[i] >> 17], 1);
    __syncthreads();
    if (t < NPB) startv[t] = cnt[t];
    __syncthreads();
    for (int off = 1; off < NPB; off <<= 1) {
        int u = (t < NPB && t >= off) ? startv[t - off] : 0;
        __syncthreads();
        if (t < NPB) startv[t] += u;
        __syncthreads();
    }
    if (t < NPB) {
        int st = startv[t] - cnt[t];
        cur[t] = st;
        int node = n0 + t;
        if (node < Nn) {
            row_off[node] = base + st;
            rdeg[node] = cnt[t];
            dinv[node] = rsqrtf((float)cnt[t] + 1.0f);
        }
    }
    __syncthreads();
    for (int i = t; i < total; i += 512) {
        unsigned v = edges[i];
        int p = atomicAdd(&cur[v >> 17], 1);
        ordered[p] = v & 0x1FFFFu;
    }
    __syncthreads();
    for (int i = t; i < total; i += 512)
        esrc[base + i] = (int)ordered[i];
}

// ---------------- tiled GEMM kernels ----------------

#define MT_FMA(AV, W0, W1, W2, W3, R)                                          \
    acc[R][0] = fmaf(AV.x, W0.x, acc[R][0]);                                   \
    acc[R][0] = fmaf(AV.y, W1.x, acc[R][0]);                                   \
    acc[R][0] = fmaf(AV.z, W2.x, acc[R][0]);                                   \
    acc[R][0] = fmaf(AV.w, W3.x, acc[R][0]);                                   \
    acc[R][1] = fmaf(AV.x, W0.y, acc[R][1]);                                   \
    acc[R][1] = fmaf(AV.y, W1.y, acc[R][1]);                                   \
    acc[R][1] = fmaf(AV.z, W2.y, acc[R][1]);                                   \
    acc[R][1] = fmaf(AV.w, W3.y, acc[R][1]);                                   \
    acc[R][2] = fmaf(AV.x, W0.z, acc[R][2]);                                   \
    acc[R][2] = fmaf(AV.y, W1.z, acc[R][2]);                                   \
    acc[R][2] = fmaf(AV.z, W2.z, acc[R][2]);                                   \
    acc[R][2] = fmaf(AV.w, W3.z, acc[R][2]);                                   \
    acc[R][3] = fmaf(AV.x, W0.w, acc[R][3]);                                   \
    acc[R][3] = fmaf(AV.y, W1.w, acc[R][3]);                                   \
    acc[R][3] = fmaf(AV.z, W2.w, acc[R][3]);                                   \
    acc[R][3] = fmaf(AV.w, W3.w, acc[R][3]);

__device__ inline void store_half4(unsigned short* dst, float a, float b,
                                   float c, float d) {
    __half2 p0 = __floats2half2_rn(a, b);
    __half2 p1 = __floats2half2_rn(c, d);
    uint2 u;
    u.x = *(unsigned*)&p0;
    u.y = *(unsigned*)&p1;
    *(uint2*)dst = u;
}

__device__ inline void store_half8(unsigned short* dst, const float* a) {
    __half2 p0 = __floats2half2_rn(a[0], a[1]);
    __half2 p1 = __floats2half2_rn(a[2], a[3]);
    __half2 p2 = __floats2half2_rn(a[4], a[5]);
    __half2 p3 = __floats2half2_rn(a[6], a[7]);
    uint4 u;
    u.x = *(unsigned*)&p0; u.y = *(unsigned*)&p1;
    u.z = *(unsigned*)&p2; u.w = *(unsigned*)&p3;
    *(uint4*)dst = u;
}

__device__ inline float4 load_half4(const unsigned short* p) {
    uint2 u = *(const uint2*)p;
    float2 f0 = __half22float2(*(__half2*)&u.x);
    float2 f1 = __half22float2(*(__half2*)&u.y);
    return make_float4(f0.x, f0.y, f1.x, f1.y);
}

// fused: bnfinal + hn = relu(agg*sc+sh)+h (h fp16, rewritten), hw = hn@W;
// store hwh = hw*dinv (fp16)
__global__ __launch_bounds__(256, 4) void k_gemmF2(const unsigned short* __restrict__ aggh,
                                                   const float* __restrict__ bnacc,
                                                   const float* __restrict__ gamma,
                                                   const float* __restrict__ beta,
                                                   unsigned short* __restrict__ hh,
                                                   const float* __restrict__ W,
                                                   const float* __restrict__ dinv,
                                                   unsigned short* __restrict__ hwh) {
    __shared__ float hs[64 * TPAD];
    __shared__ float ws[64 * 64];
    __shared__ float bsc[64], bsh[64];
    int t = threadIdx.x;
    int n0 = blockIdx.x * 64;

    for (int f = t; f < 1024; f += 256)
        ((float4*)ws)[f] = ((const float4*)W)[f];

    if (t < 64) {   // bn finalize: reduce 128 shards
        float s = 0.f, s2 = 0.f;
        for (int shd = 0; shd < NSH; shd++) {
            s  += bnacc[shd * 128 + t];
            s2 += bnacc[shd * 128 + 64 + t];
        }
        float mean = s / (float)Nn;
        float var = fmaxf(s2 / (float)Nn - mean * mean, 0.f);
        float scv = gamma[t] * rsqrtf(var + BN_EPS);
        bsc[t] = scv;
        bsh[t] = beta[t] - mean * scv;
    }
    __syncthreads();

    for (int f = t; f < 1024; f += 256) {
        int row = f >> 4, c4 = (f & 15) * 4;
        int node = n0 + row;
        if (node < Nn) {
            float4 a  = load_half4(aggh + (size_t)node * Hd + c4);
            float4 ho = load_half4(hh + (size_t)node * Hd + c4);
            float4 sc = ((const float4*)bsc)[f & 15];
            float4 sh = ((const float4*)bsh)[f & 15];
            float4 r4;
            r4.x = fmaxf(fmaf(a.x, sc.x, sh.x), 0.f) + ho.x;
            r4.y = fmaxf(fmaf(a.y, sc.y, sh.y), 0.f) + ho.y;
            r4.z = fmaxf(fmaf(a.z, sc.z, sh.z), 0.f) + ho.z;
            r4.w = fmaxf(fmaf(a.w, sc.w, sh.w), 0.f) + ho.w;
            store_half4(hh + (size_t)node * Hd + c4, r4.x, r4.y, r4.z, r4.w);
            *(float4*)&hs[row * TPAD + c4] = r4;
        } else {
            *(float4*)&hs[row * TPAD + c4] = make_float4(0.f, 0.f, 0.f, 0.f);
        }
    }
    __syncthreads();

    int i = t >> 4, j = t & 15;
    float acc[4][4] = {};
#pragma unroll 2
    for (int k = 0; k < 64; k += 4) {
        float4 w0 = *(const float4*)&ws[(k + 0) * 64 + 4 * j];
        float4 w1 = *(const float4*)&ws[(k + 1) * 64 + 4 * j];
        float4 w2 = *(const float4*)&ws[(k + 2) * 64 + 4 * j];
        float4 w3 = *(const float4*)&ws[(k + 3) * 64 + 4 * j];
        float4 a0 = *(const float4*)&hs[(4 * i + 0) * TPAD + k];
        float4 a1 = *(const float4*)&hs[(4 * i + 1) * TPAD + k];
        float4 a2 = *(const float4*)&hs[(4 * i + 2) * TPAD + k];
        float4 a3 = *(const float4*)&hs[(4 * i + 3) * TPAD + k];
        MT_FMA(a0, w0, w1, w2, w3, 0)
        MT_FMA(a1, w0, w1, w2, w3, 1)
        MT_FMA(a2, w0, w1, w2, w3, 2)
        MT_FMA(a3, w0, w1, w2, w3, 3)
    }
#pragma unroll
    for (int r = 0; r < 4; r++) {
        int node = n0 + 4 * i + r;
        if (node < Nn) {
            float dv = dinv[node];
            store_half4(hwh + (size_t)node * Hd + 4 * j,
                        acc[r][0] * dv, acc[r][1] * dv, acc[r][2] * dv,
                        acc[r][3] * dv);
        }
    }
}

// fused: h = x@we+be (write hh fp16), hw = h@W0; store hwh = hw*dinv (fp16)
__global__ __launch_bounds__(256, 4) void k_embed_gemm2(const float* __restrict__ x,
                                                        const float* __restrict__ we,
                                                        const float* __restrict__ be,
                                                        const float* __restrict__ W,
                                                        unsigned short* __restrict__ hh,
                                                        const float* __restrict__ dinv,
                                                        unsigned short* __restrict__ hwh) {
    __shared__ float uni[64 * XPAD + 32 * 64];
    __shared__ float hs[64 * TPAD];
    __shared__ float bes[64];
    float* xs  = uni;
    float* wes = uni + 64 * XPAD;
    float* ws  = uni;
    int t = threadIdx.x;
    int n0 = blockIdx.x * 64;

    for (int f = t; f < 512; f += 256)
        ((float4*)wes)[f] = ((const float4*)we)[f];
    if (t < 64) bes[t] = be[t];

    for (int f = t; f < 512; f += 256) {
        int row = f >> 3, c4 = (f & 7) * 4;
        int node = n0 + row;
        float4 v = (node < Nn) ? *(const float4*)(x + (size_t)node * Fi + c4)
                               : make_float4(0.f, 0.f, 0.f, 0.f);
        *(float4*)&xs[row * XPAD + c4] = v;
    }
    __syncthreads();

    int i = t >> 4, j = t & 15;
    {
        float acc[4][4];
#pragma unroll
        for (int r = 0; r < 4; r++)
#pragma unroll
            for (int c = 0; c < 4; c++) acc[r][c] = bes[4 * j + c];
#pragma unroll 2
        for (int k = 0; k < 32; k += 4) {
            float4 w0 = *(const float4*)&wes[(k + 0) * 64 + 4 * j];
            float4 w1 = *(const float4*)&wes[(k + 1) * 64 + 4 * j];
            float4 w2 = *(const float4*)&wes[(k + 2) * 64 + 4 * j];
            float4 w3 = *(const float4*)&wes[(k + 3) * 64 + 4 * j];
            float4 a0 = *(const float4*)&xs[(4 * i + 0) * XPAD + k];
            float4 a1 = *(const float4*)&xs[(4 * i + 1) * XPAD + k];
            float4 a2 = *(const float4*)&xs[(4 * i + 2) * XPAD + k];
            float4 a3 = *(const float4*)&xs[(4 * i + 3) * XPAD + k];
            MT_FMA(a0, w0, w1, w2, w3, 0)
            MT_FMA(a1, w0, w1, w2, w3, 1)
            MT_FMA(a2, w0, w1, w2, w3, 2)
            MT_FMA(a3, w0, w1, w2, w3, 3)
        }
#pragma unroll
        for (int r = 0; r < 4; r++) {
            int node = n0 + 4 * i + r;
            float4 hv = make_float4(acc[r][0], acc[r][1], acc[r][2], acc[r][3]);
            *(float4*)&hs[(4 * i + r) * TPAD + 4 * j] = hv;
            if (node < Nn)
                store_half4(hh + (size_t)node * Hd + 4 * j, hv.x, hv.y, hv.z, hv.w);
        }
    }
    __syncthreads();
    for (int f = t; f < 1024; f += 256)
        ((float4*)ws)[f] = ((const float4*)W)[f];
    __syncthreads();
    {
        float acc[4][4] = {};
#pragma unroll 2
        for (int k = 0; k < 64; k += 4) {
            float4 w0 = *(const float4*)&ws[(k + 0) * 64 + 4 * j];
            float4 w1 = *(const float4*)&ws[(k + 1) * 64 + 4 * j];
            float4 w2 = *(const float4*)&ws[(k + 2) * 64 + 4 * j];
            float4 w3 = *(const float4*)&ws[(k + 3) * 64 + 4 * j];
            float4 a0 = *(const float4*)&hs[(4 * i + 0) * TPAD + k];
            float4 a1 = *(const float4*)&hs[(4 * i + 1) * TPAD + k];
            float4 a2 = *(const float4*)&hs[(4 * i + 2) * TPAD + k];
            float4 a3 = *(const float4*)&hs[(4 * i + 3) * TPAD + k];
            MT_FMA(a0, w0, w1, w2, w3, 0)
            MT_FMA(a1, w0, w1, w2, w3, 1)
            MT_FMA(a2, w0, w1, w2, w3, 2)
            MT_FMA(a3, w0, w1, w2, w3, 3)
        }
#pragma unroll
        for (int r = 0; r < 4; r++) {
            int node = n0 + 4 * i + r;
            if (node < Nn) {
                float dv = dinv[node];
                store_half4(hwh + (size_t)node * Hd + 4 * j,
                            acc[r][0] * dv, acc[r][1] * dv, acc[r][2] * dv,
                            acc[r][3] * dv);
            }
        }
    }
}

// ---------------- gather / pool / head ----------------

// gather on pre-scaled rows: agg = (sum_src hwh[src] + hwh[node]) * dinv[node] + bias
// 8 lanes/node, uint4 (16B) loads, 8-deep unrolled; writes aggh fp16
__global__ __launch_bounds__(256) void k_gatherH(const unsigned short* __restrict__ hwh,
                                                 const float* __restrict__ dinv,
                                                 const int* __restrict__ row_off,
                                                 const int* __restrict__ rdeg,
                                                 const int* __restrict__ esrc,
                                                 const float* __restrict__ bias,
                                                 unsigned short* __restrict__ aggh,
                                                 float* __restrict__ bnacc) {
    int g = threadIdx.x >> 3;   // 32 node slots
    int l = threadIdx.x & 7;    // lane in node group
    int node = blockIdx.x * 32 + g;   // Nn % 32 == 0
    float di = dinv[node];
    float acc[8];

    uint4 v = *(const uint4*)(hwh + (size_t)node * Hd + l * 8);
#pragma unroll
    for (int q = 0; q < 4; q++) {
        float2 f = __half22float2(*(__half2*)(((unsigned*)&v) + q));
        acc[2 * q]     = f.x;
        acc[2 * q + 1] = f.y;
    }

    int e = row_off[node];
    int e1 = e + rdeg[node];
    for (; e + 7 < e1; e += 8) {
        uint4 vv[8];
#pragma unroll
        for (int u = 0; u < 8; u++)
            vv[u] = *(const uint4*)(hwh + (size_t)esrc[e + u] * Hd + l * 8);
#pragma unroll
        for (int u = 0; u < 8; u++) {
#pragma unroll
            for (int q = 0; q < 4; q++) {
                float2 f = __half22float2(*(__half2*)(((unsigned*)&vv[u]) + q));
                acc[2 * q]     += f.x;
                acc[2 * q + 1] += f.y;
            }
        }
    }
    for (; e + 1 < e1; e += 2) {
        uint4 v0 = *(const uint4*)(hwh + (size_t)esrc[e] * Hd + l * 8);
        uint4 v1 = *(const uint4*)(hwh + (size_t)esrc[e + 1] * Hd + l * 8);
#pragma unroll
        for (int q = 0; q < 4; q++) {
            float2 f0 = __half22float2(*(__half2*)(((unsigned*)&v0) + q));
            float2 f1 = __half22float2(*(__half2*)(((unsigned*)&v1) + q));
            acc[2 * q]     += f0.x + f1.x;
            acc[2 * q + 1] += f0.y + f1.y;
        }
    }
    if (e < e1) {
        uint4 v0 = *(const uint4*)(hwh + (size_t)esrc[e] * Hd + l * 8);
#pragma unroll
        for (int q = 0; q < 4; q++) {
            float2 f0 = __half22float2(*(__half2*)(((unsigned*)&v0) + q));
            acc[2 * q]     += f0.x;
            acc[2 * q + 1] += f0.y;
        }
    }

#pragma unroll
    for (int q = 0; q < 8; q++)
        acc[q] = fmaf(acc[q], di, bias[l * 8 + q]);

    store_half8(aggh + (size_t)node * Hd + l * 8, acc);

    // bn stats: block reduce over 32 node slots, sharded atomics
    __shared__ float ls[2048];
    *(float4*)&ls[g * 64 + l * 8]     = make_float4(acc[0], acc[1], acc[2], acc[3]);
    *(float4*)&ls[g * 64 + l * 8 + 4] = make_float4(acc[4], acc[5], acc[6], acc[7]);
    __syncthreads();
    int t = threadIdx.x;
    if (t < 64) {
        float s = 0.f, s2 = 0.f;
#pragma unroll
        for (int gg = 0; gg < 32; gg++) {
            float vv = ls[gg * 64 + t];
            s += vv;
            s2 = fmaf(vv, vv, s2);
        }
        float* a = bnacc + (blockIdx.x & (NSH - 1)) * 128;
        atomicAdd(&a[t], s);
        atomicAdd(&a[64 + t], s2);
    }
}

// fused: bnfinal + final bn-apply + relu + residual + per-graph mean pool
__global__ __launch_bounds__(1024) void k_poolF(const unsigned short* __restrict__ aggh,
                                                const float* __restrict__ bnacc,
                                                const float* __restrict__ gamma,
                                                const float* __restrict__ beta,
                                                const unsigned short* __restrict__ hh,
                                                const int* __restrict__ gstart,
                                                float* __restrict__ pooled) {
    __shared__ float ls[1024];
    __shared__ float bsc[64], bsh[64];
    int g = blockIdx.x;
    int t = threadIdx.x;
    if (t < 64) {
        float s = 0.f, s2 = 0.f;
        for (int shd = 0; shd < NSH; shd++) {
            s  += bnacc[shd * 128 + t];
            s2 += bnacc[shd * 128 + 64 + t];
        }
        float mean = s / (float)Nn;
        float var = fmaxf(s2 / (float)Nn - mean * mean, 0.f);
        float scv = gamma[t] * rsqrtf(var + BN_EPS);
        bsc[t] = scv;
        bsh[t] = beta[t] - mean * scv;
    }
    __syncthreads();
    int ch = t & 63, sl = t >> 6;
    float sc = bsc[ch], shv = bsh[ch];
    int n0 = gstart[g], n1 = gstart[g + 1];
    float s = 0.f;
    for (int n = n0 + sl; n < n1; n += 16) {
        float a  = __half2float(((const __half*)aggh)[(size_t)n * Hd + ch]);
        float ho = __half2float(((const __half*)hh)[(size_t)n * Hd + ch]);
        s += fmaxf(fmaf(a, sc, shv), 0.f) + ho;
    }
    ls[t] = s;
    __syncthreads();
    if (t < 64) {
        float acc = 0.f;
#pragma unroll
        for (int k = 0; k < 16; k++) acc += ls[k * 64 + t];
        float cnt = (float)(n1 - n0);
        pooled[g * Hd + t] = acc / fmaxf(cnt, 1.0f);
    }
}

__global__ __launch_bounds__(256) void k_head(const float* __restrict__ pooled,
                                              const float* __restrict__ w1,
                                              const float* __restrict__ b1,
                                              const float* __restrict__ w2,
                                              const float* __restrict__ b2,
                                              float* __restrict__ out) {
    __shared__ float sw1[Hd * 32], sw2[32], sb1[32];
    int t = threadIdx.x;
    for (int i = t; i < Hd * 32; i += 256) sw1[i] = w1[i];
    if (t < 32) { sw2[t] = w2[t]; sb1[t] = b1[t]; }
    __syncthreads();
    float acc2[32];
#pragma unroll
    for (int k = 0; k < 32; k++) acc2[k] = sb1[k];
    for (int j = 0; j < Hd; j++) {
        float pj = pooled[t * Hd + j];
#pragma unroll
        for (int k = 0; k < 32; k++) acc2[k] = fmaf(pj, sw1[j * 32 + k], acc2[k]);
    }
    float o = b2[0];
#pragma unroll
    for (int k = 0; k < 32; k++) o += fmaxf(acc2[k], 0.f) * sw2[k];
    out[t] = o;
}

// ---------------- launch ----------------

extern "C" void kernel_launch(void* const* d_in, const int* in_sizes, int n_in,
                              void* d_out, int out_size, void* d_ws, size_t ws_size,
                              hipStream_t stream) {
    const float* x       = (const float*)d_in[0];
    const int*   eidx    = (const int*)d_in[1];
    const int*   batch   = (const int*)d_in[2];
    const float* w_embed = (const float*)d_in[3];
    const float* b_embed = (const float*)d_in[4];
    const float* conv_W  = (const float*)d_in[5];
    const float* conv_b  = (const float*)d_in[6];
    const float* gamma   = (const float*)d_in[7];
    const float* beta    = (const float*)d_in[8];
    const float* w1      = (const float*)d_in[9];
    const float* b1      = (const float*)d_in[10];
    const float* w2      = (const float*)d_in[11];
    const float* b2      = (const float*)d_in[12];
    const int* src = eidx;
    const int* dst = eidx + Ne;

    char* p = (char*)d_ws;
    auto alloc = [&](size_t bytes) -> void* {
        void* r = (void*)p;
        p += (bytes + 255) / 256 * 256;
        return r;
    };
    unsigned short* hh  = (unsigned short*)alloc((size_t)Nn * Hd * 2);
    unsigned short* hwh = (unsigned short*)alloc((size_t)Nn * Hd * 2);
    unsigned short* aggh = (unsigned short*)alloc((size_t)Nn * Hd * 2);
    int*      row_off = (int*)alloc((size_t)Nn * 4);
    int*      rdeg    = (int*)alloc((size_t)Nn * 4);
    float*    dinv    = (float*)alloc((size_t)Nn * 4);
    int*      esrc    = (int*)alloc((size_t)NBINS * BSLOT * 4);
    unsigned* tpack   = (unsigned*)alloc((size_t)NBLK * CHUNK * 4);
    unsigned short* idx16 = (unsigned short*)alloc((size_t)NBLK * IDXW * 2);
    float*    bnacc   = (float*)alloc((size_t)Ll * NSH * 128 * 4);
    float*    pooled  = (float*)alloc((size_t)Gg * Hd * 4);
    int*      gstart  = (int*)alloc((size_t)(Gg + 1) * 4);
    (void)ws_size; (void)in_sizes; (void)n_in; (void)out_size;

    const int NB_G32 = Nn / 32;              // 3125 gather blocks

    hipMemsetAsync(bnacc, 0, (size_t)Ll * NSH * 128 * 4, stream);

    k_part<<<NBLK, 256, 0, stream>>>(src, dst, tpack, idx16);
    k_csr2<<<NBINS + 1, 512, 0, stream>>>(tpack, idx16, batch, esrc, row_off,
                                          rdeg, dinv, gstart);

    k_embed_gemm2<<<NGB, 256, 0, stream>>>(x, w_embed, b_embed, conv_W, hh, dinv, hwh);

    for (int i = 0; i < Ll; i++) {
        if (i > 0)
            k_gemmF2<<<NGB, 256, 0, stream>>>(aggh, bnacc + (size_t)(i - 1) * NSH * 128,
                                              gamma + (size_t)(i - 1) * Hd,
                                              beta + (size_t)(i - 1) * Hd, hh,
                                              conv_W + (size_t)i * Hd * Hd, dinv, hwh);
        k_gatherH<<<NB_G32, 256, 0, stream>>>(hwh, dinv, row_off, rdeg, esrc,
                                              conv_b + (size_t)i * Hd, aggh,
                                              bnacc + (size_t)i * NSH * 128);
    }

    k_poolF<<<Gg, 1024, 0, stream>>>(aggh, bnacc + (size_t)(Ll - 1) * NSH * 128,
                                     gamma + (size_t)(Ll - 1) * Hd,
                                     beta + (size_t)(Ll - 1) * Hd, hh, gstart, pooled);
    k_head<<<1, 256, 0, stream>>>(pooled, w1, b1, w2, b2, (float*)d_out);
}